// Round 9
// baseline (289.473 us; speedup 1.0000x reference)
//
#include <hip/hip_runtime.h>
#include <hip/hip_bf16.h>

typedef __attribute__((ext_vector_type(8))) short short8;
typedef __attribute__((ext_vector_type(4))) float f32x4;

#define GLOBAL_AS __attribute__((address_space(1)))
#define LDS_AS    __attribute__((address_space(3)))

__device__ __forceinline__ unsigned short f2bf(float f) {
    union { float f; unsigned int u; } v; v.f = f;
    unsigned int r = v.u + 0x7FFFu + ((v.u >> 16) & 1u);  // RNE
    return (unsigned short)(r >> 16);
}

// packed f32x2 -> bf16x2 (v_cvt_pk_bf16_f32 on gfx950), RNE
__device__ __forceinline__ unsigned int pk_bf16(float a, float b) {
    union { __hip_bfloat162 h; unsigned int u; } c;
    c.h = __float22bfloat162_rn(float2{a, b});
    return c.u;
}

__device__ __forceinline__ short8 cvt8v(float4 a, float4 b) {
    union { short8 s; unsigned int u[4]; } c;
    c.u[0] = pk_bf16(a.x, a.y); c.u[1] = pk_bf16(a.z, a.w);
    c.u[2] = pk_bf16(b.x, b.y); c.u[3] = pk_bf16(b.z, b.w);
    return c.s;
}

// async global->LDS, 16B per lane; lds base wave-uniform, lane i lands at +i*16
__device__ __forceinline__ void async_ld16(const unsigned short* g, unsigned short* l) {
    __builtin_amdgcn_global_load_lds((const GLOBAL_AS unsigned int*)g,
                                     (LDS_AS unsigned int*)l, 16, 0, 0);
}

// counted vmcnt wait + raw barrier (T4): never drain the prefetch queue
#define WAITV(N) asm volatile("s_waitcnt vmcnt(" #N ")" ::: "memory")
#define BARSYNC() do { __builtin_amdgcn_s_barrier(); __builtin_amdgcn_sched_barrier(0); } while (0)

// ---------------------------------------------------------------------------
// Elementwise f32 -> bf16 (RNE). 8 elems/thread.
// ---------------------------------------------------------------------------
__global__ __launch_bounds__(256) void cvt_bf16(
    const float* __restrict__ src, unsigned short* __restrict__ dst)
{
    const size_t i = ((size_t)blockIdx.x * 256 + threadIdx.x) * 8;
    float4 a = *(const float4*)(src + i);
    float4 b = *(const float4*)(src + i + 4);
    *(short8*)(dst + i) = cvt8v(a, b);
}

// ---------------------------------------------------------------------------
// Transpose+convert: dst[n][k] bf16 = src[k][n] f32. Grid (N/64, K/64).
// ---------------------------------------------------------------------------
__global__ __launch_bounds__(256) void transpose_cvt(
    const float* __restrict__ src, unsigned short* __restrict__ dst, int K, int N)
{
    __shared__ unsigned short t[64][72];
    const int tid = threadIdx.x;
    const int n0 = blockIdx.x * 64, k0 = blockIdx.y * 64;
    #pragma unroll
    for (int it = 0; it < 4; ++it) {
        int r = it * 16 + (tid >> 4);
        int c = (tid & 15) * 4;
        float4 v = *(const float4*)(src + (size_t)(k0 + r) * N + n0 + c);
        t[r][c] = f2bf(v.x); t[r][c + 1] = f2bf(v.y);
        t[r][c + 2] = f2bf(v.z); t[r][c + 3] = f2bf(v.w);
    }
    __syncthreads();
    const int nr = tid >> 2, kg = (tid & 3) * 16;
    short8 o0, o1;
    #pragma unroll
    for (int j = 0; j < 8; ++j) { o0[j] = (short)t[kg + j][nr]; o1[j] = (short)t[kg + 8 + j][nr]; }
    *(short8*)(dst + (size_t)(n0 + nr) * K + k0 + kg) = o0;
    *(short8*)(dst + (size_t)(n0 + nr) * K + k0 + kg + 8) = o1;
}

// ---------------------------------------------------------------------------
// GEMM v7: 128x128 tile, BK=32, QUAD-buffered (As0-3/Bs0-3, 64KB LDS) with
// COUNTED vmcnt + raw s_barrier (T4, m218 pattern). Rounds 6-8 proved all
// __syncthreads variants identical (~84us/GEMM): the compiler's vmcnt(0)
// drain at every barrier is the structural stall (m233: 72% of 2-phase).
// Here each tile's wait is `s_waitcnt vmcnt(8)` = retire ONLY the oldest 4
// loads (the tile about to be read); 8 prefetch loads stay in flight across
// the barrier. Loads fly ~2.5 tiles (~500cy) before their wait.
// Schedule (tile t lives in buf[t%4]; 4 loads/wave/tile):
//   prologue: stage t0,t1,t2                       (12 outstanding)
//   body sub j: WAITV(8); BAR; stage t+3; compute t  (invariant: 12 at top)
//   tail (last 4 tiles): waits 8,8,4,0 (hand-counted, exact)
// Race proof: stage into a buffer happens >=3 barriers after its last
// reader passed (issue-order + barrier rendezvous).
// Bank swizzle (64B rows, 4 chunks): fetch chunk (l&3)^(row&3), read chunk
// quad^(l15&3) — same involution both sides, uniform 8 lanes/chunk.
// XCD-chunked block swizzle kept (FETCH 175->80MB).
// ---------------------------------------------------------------------------
__device__ __forceinline__ void stage_tile(
    const unsigned short* __restrict__ Ag, const unsigned short* __restrict__ Bg,
    unsigned short (*Asb)[32], unsigned short (*Bsb)[32],
    int m0, int n0, int K, int k, int w, int srow, int scol)
{
    #pragma unroll
    for (int c = 0; c < 2; ++c) {
        const int rb = c * 64 + w * 16;
        async_ld16(Ag + (size_t)(m0 + rb + srow) * K + k + scol, &Asb[rb][0]);
        async_ld16(Bg + (size_t)(n0 + rb + srow) * K + k + scol, &Bsb[rb][0]);
    }
}

__device__ __forceinline__ void compute_tile(
    const unsigned short (*Asb)[32], const unsigned short (*Bsb)[32],
    int rw, int cw, int l15, int quad, f32x4 acc[4][4])
{
    const int pc = (quad ^ (l15 & 3)) * 8;   // read-side swizzled chunk
    short8 af[4], bf[4];
    #pragma unroll
    for (int i = 0; i < 4; ++i)
        af[i] = *(const short8*)&Asb[rw + i * 16 + l15][pc];
    #pragma unroll
    for (int j = 0; j < 4; ++j)
        bf[j] = *(const short8*)&Bsb[cw + j * 16 + l15][pc];
    #pragma unroll
    for (int i = 0; i < 4; ++i)
        #pragma unroll
        for (int j = 0; j < 4; ++j)
            acc[i][j] = __builtin_amdgcn_mfma_f32_16x16x32_bf16(af[i], bf[j], acc[i][j], 0, 0, 0);
}

template<bool OUT_F32>
__global__ __launch_bounds__(256, 2) void gemm_bt(
    const unsigned short* __restrict__ Ab, const unsigned short* __restrict__ Bt,
    void* __restrict__ Cv, int M, int N, int K)   // requires K % 128 == 0
{
    __shared__ __align__(16) unsigned short As0[128][32], Bs0[128][32];
    __shared__ __align__(16) unsigned short As1[128][32], Bs1[128][32];
    __shared__ __align__(16) unsigned short As2[128][32], Bs2[128][32];
    __shared__ __align__(16) unsigned short As3[128][32], Bs3[128][32];

    const int tid = threadIdx.x, lane = tid & 63, w = tid >> 6;
    const int quad = lane >> 4, l15 = lane & 15;

    // XCD-chunked bijective swizzle (nwg % 8 == 0 for both GEMM grids)
    const int nwg = gridDim.x * gridDim.y;
    int lin = blockIdx.y * gridDim.x + blockIdx.x;
    lin = (lin & 7) * (nwg >> 3) + (lin >> 3);
    const int m0 = (lin / gridDim.x) * 128, n0 = (lin % gridDim.x) * 128;

    const int rw = (w >> 1) * 64, cw = (w & 1) * 64;   // wave's output quadrant

    const f32x4 zero = {0.f, 0.f, 0.f, 0.f};
    f32x4 acc[4][4];
    #pragma unroll
    for (int i = 0; i < 4; ++i)
        #pragma unroll
        for (int j = 0; j < 4; ++j) acc[i][j] = zero;

    // staging map: 4 lanes/row (64B row), 16B/lane, chunk XOR'd by row&3
    const int srow = lane >> 2;
    const int scol = (((lane & 3) ^ (srow & 3)) * 8);

    // -------- prologue: tiles 0,1,2 -> buf0,1,2 (12 loads/wave) --------
    stage_tile(Ab, Bt, As0, Bs0, m0, n0, K, 0,  w, srow, scol);
    stage_tile(Ab, Bt, As1, Bs1, m0, n0, K, 32, w, srow, scol);
    stage_tile(Ab, Bt, As2, Bs2, m0, n0, K, 64, w, srow, scol);

    // -------- body: 4 tiles per iteration; last 4 tiles peeled --------
    for (int k0 = 0; k0 + 224 < K; k0 += 128) {
        WAITV(8); BARSYNC();
        stage_tile(Ab, Bt, As3, Bs3, m0, n0, K, k0 + 96, w, srow, scol);
        compute_tile(As0, Bs0, rw, cw, l15, quad, acc);

        WAITV(8); BARSYNC();
        stage_tile(Ab, Bt, As0, Bs0, m0, n0, K, k0 + 128, w, srow, scol);
        compute_tile(As1, Bs1, rw, cw, l15, quad, acc);

        WAITV(8); BARSYNC();
        stage_tile(Ab, Bt, As1, Bs1, m0, n0, K, k0 + 160, w, srow, scol);
        compute_tile(As2, Bs2, rw, cw, l15, quad, acc);

        WAITV(8); BARSYNC();
        stage_tile(Ab, Bt, As2, Bs2, m0, n0, K, k0 + 192, w, srow, scol);
        compute_tile(As3, Bs3, rw, cw, l15, quad, acc);
    }

    // -------- tail: tiles K/32-4 .. K/32-1 (bufs 0..3); waits 8,8,4,0 ----
    {
        const int kt = K - 128;
        WAITV(8); BARSYNC();
        stage_tile(Ab, Bt, As3, Bs3, m0, n0, K, kt + 96, w, srow, scol);
        compute_tile(As0, Bs0, rw, cw, l15, quad, acc);

        WAITV(8); BARSYNC();
        compute_tile(As1, Bs1, rw, cw, l15, quad, acc);

        WAITV(4); BARSYNC();
        compute_tile(As2, Bs2, rw, cw, l15, quad, acc);

        WAITV(0); BARSYNC();
        compute_tile(As3, Bs3, rw, cw, l15, quad, acc);
    }

    #pragma unroll
    for (int i = 0; i < 4; ++i) {
        const int row = m0 + rw + i * 16 + quad * 4;
        #pragma unroll
        for (int j = 0; j < 4; ++j) {
            const int col = n0 + cw + j * 16 + l15;
            #pragma unroll
            for (int r = 0; r < 4; ++r) {
                if constexpr (OUT_F32)
                    ((float*)Cv)[(size_t)(row + r) * N + col] = acc[i][j][r];
                else
                    ((unsigned short*)Cv)[(size_t)(row + r) * N + col] = f2bf(acc[i][j][r]);
            }
        }
    }
}

// ---------------------------------------------------------------------------
// Flash MQA v6 (unchanged — proven): swapped-operand QK^T with in-register P
// pack into the PV B-fragment; K/V double-buffered, one barrier per
// iteration; O^T epilogue transpose through LDS; fixed-max softmax M=12;
// denominator via ones rows 128..143 of VT.
// ---------------------------------------------------------------------------
__global__ __launch_bounds__(256) void mqa_flash(
    const unsigned short* __restrict__ qkv,  // [B*S, 2304] bf16
    unsigned short* __restrict__ attn)       // [B*S, 2048] bf16
{
    const int S = 2048, QKVW = 2304;
    __shared__ __align__(16) union {
        struct {
            unsigned short Ks[2][32][136];   // [buf][permuted key][d]
            unsigned short VT[2][144][44];   // [buf][d][key]; rows 128..143 ones
        } s;
        unsigned short T[4][32][136];        // epilogue per-wave O transpose
    } sm;

    const int tid = threadIdx.x, lane = tid & 63, w = tid >> 6;
    const int quad = lane >> 4, l15 = lane & 15;
    const int bid = blockIdx.x;
    const int qb = bid & 15;          // 16 q-blocks of 128 rows
    const int h  = (bid >> 4) & 15;
    const int b  = bid >> 8;

    // ones rows for the denominator, both buffers (cols 0..31 are read)
    for (int i = tid; i < 2 * 16 * 32; i += 256)
        sm.s.VT[i >> 9][128 + ((i >> 5) & 15)][i & 31] = 0x3F80;

    const unsigned short* base = qkv + (size_t)b * S * QKVW;

    // Q fragments (QK B-operand: n=q=l15, k=quad*8+j — same layout as A-frag)
    short8 qf[2][4];
    #pragma unroll
    for (int sub = 0; sub < 2; ++sub) {
        const int row = qb * 128 + w * 32 + sub * 16 + l15;
        #pragma unroll
        for (int ds = 0; ds < 4; ++ds)
            qf[sub][ds] = *(const short8*)(base + (size_t)row * QKVW + h * 128 + ds * 32 + quad * 8);
    }

    const f32x4 zero = {0.f, 0.f, 0.f, 0.f};
    f32x4 o[2][9];                      // O^T: o[sub][dsub][r] = O[d=dsub*16+quad*4+r][q=l15]
    #pragma unroll
    for (int sub = 0; sub < 2; ++sub)
        #pragma unroll
        for (int d = 0; d < 9; ++d) o[sub][d] = zero;

    // staging maps
    const int krow = tid & 31, kdg = tid >> 5;            // K: key, 16-d group
    const int kpr  = ((krow & 1) << 4) | (krow >> 1);     // even/odd permuted row
    const int vkp  = tid & 15, vdg = tid >> 4;            // V: key pair, 8-d group

    const unsigned short* kp = base + (size_t)krow * QKVW + 2048 + kdg * 16;
    const unsigned short* vp = base + (size_t)(2 * vkp) * QKVW + 2176 + vdg * 8;

    // prologue: tile 0 into regs
    short8 k0v = *(const short8*)kp;
    short8 k1v = *(const short8*)(kp + 8);
    short8 v0v = *(const short8*)vp;
    short8 v1v = *(const short8*)(vp + QKVW);

    for (int kb = 0; kb < S; kb += 32) {
        const int p = (kb >> 5) & 1;

        // write tile kb into buf[p] (compiler inserts the vmcnt wait; loads
        // were issued one iteration ago, so it's cheap). Prior readers of
        // buf[p] (iter kb-2) are fenced by iter kb-1's barrier.
        *(short8*)(&sm.s.Ks[p][kpr][kdg * 16]) = k0v;
        *(short8*)(&sm.s.Ks[p][kpr][kdg * 16 + 8]) = k1v;
        #pragma unroll
        for (int j = 0; j < 8; ++j) {
            unsigned int pkv = (unsigned int)(unsigned short)v0v[j]
                             | ((unsigned int)(unsigned short)v1v[j] << 16);
            *(unsigned int*)(&sm.s.VT[p][vdg * 8 + j][vkp * 2]) = pkv;
        }

        // issue next tile loads (waited at the TOP of the next iteration:
        // latency hides under the barrier + full compute phase below)
        if (kb + 32 < S) {
            kp += 32 * QKVW; vp += 32 * QKVW;
            k0v = *(const short8*)kp;
            k1v = *(const short8*)(kp + 8);
            v0v = *(const short8*)vp;
            v1v = *(const short8*)(vp + QKVW);
        }

        __syncthreads();   // single barrier per iteration (double-buffered)

        __builtin_amdgcn_s_setprio(1);

        // --- QK^T swapped: sc[sub][par] = mfma(K_par, Q_sub) -> S[key][q];
        //     lane holds S[key = 8*quad + 2r + par][q = l15] ---
        f32x4 sc[2][2];
        sc[0][0] = zero; sc[0][1] = zero; sc[1][0] = zero; sc[1][1] = zero;
        #pragma unroll
        for (int ds = 0; ds < 4; ++ds) {
            short8 kf0 = *(const short8*)(&sm.s.Ks[p][l15][ds * 32 + quad * 8]);      // even keys
            short8 kf1 = *(const short8*)(&sm.s.Ks[p][16 + l15][ds * 32 + quad * 8]); // odd keys
            #pragma unroll
            for (int sub = 0; sub < 2; ++sub) {
                sc[sub][0] = __builtin_amdgcn_mfma_f32_16x16x32_bf16(kf0, qf[sub][ds], sc[sub][0], 0, 0, 0);
                sc[sub][1] = __builtin_amdgcn_mfma_f32_16x16x32_bf16(kf1, qf[sub][ds], sc[sub][1], 0, 0, 0);
            }
        }

        // --- exp + in-register P pack: u[r] = (key 8q+2r, key 8q+2r+1) ->
        //     exactly the PV B-fragment (k=quad*8+j, n=q=l15). No LDS. ---
        const float scale = 0.08838834764831845f;  // 128^-0.5
        short8 pf[2];
        #pragma unroll
        for (int sub = 0; sub < 2; ++sub) {
            union { short8 sv; unsigned int u[4]; } c;
            #pragma unroll
            for (int r = 0; r < 4; ++r) {
                float e0 = __expf(fmaf(sc[sub][0][r], scale, -12.f));
                float e1 = __expf(fmaf(sc[sub][1][r], scale, -12.f));
                c.u[r] = pk_bf16(e0, e1);
            }
            pf[sub] = c.sv;
        }

        // --- PV: o^T = mfma(V^T, P); V-frags read once, used for both subs ---
        #pragma unroll
        for (int dsub = 0; dsub < 9; ++dsub) {
            short8 vf = *(const short8*)(&sm.s.VT[p][dsub * 16 + l15][quad * 8]);
            o[0][dsub] = __builtin_amdgcn_mfma_f32_16x16x32_bf16(vf, pf[0], o[0][dsub], 0, 0, 0);
            o[1][dsub] = __builtin_amdgcn_mfma_f32_16x16x32_bf16(vf, pf[1], o[1][dsub], 0, 0, 0);
        }

        __builtin_amdgcn_s_setprio(0);
    }

    __syncthreads();   // all compute reads of K/V buffers done before overlay

    // epilogue: per-wave O^T -> O transpose through LDS, then coalesced store.
    // den = o[sub][8] (ones-rows MFMA) is uniform across quad/r: inv per q=l15.
    #pragma unroll
    for (int sub = 0; sub < 2; ++sub) {
        const float inv = 1.0f / o[sub][8][0];
        #pragma unroll
        for (int dsub = 0; dsub < 8; ++dsub) {
            unsigned int lo = pk_bf16(o[sub][dsub][0] * inv, o[sub][dsub][1] * inv);
            unsigned int hi = pk_bf16(o[sub][dsub][2] * inv, o[sub][dsub][3] * inv);
            unsigned int* dst = (unsigned int*)&sm.T[w][sub * 16 + l15][dsub * 16 + quad * 4];
            dst[0] = lo; dst[1] = hi;
        }
    }
    __syncthreads();

    const size_t rowbase = (size_t)b * S + qb * 128 + w * 32;
    #pragma unroll
    for (int pass = 0; pass < 8; ++pass) {
        const int row = pass * 4 + quad;
        short8 ov = *(const short8*)(&sm.T[w][row][l15 * 8]);
        *(short8*)(&attn[(rowbase + row) * 2048 + h * 128 + l15 * 8]) = ov;
    }
}

// ---------------------------------------------------------------------------
// ws layout (ushort units), total 35.65 MB (proven-safe footprint):
//   R0 [0, 9437184): qkv bf16 [4096][2304]; after mqa, woutT [2048][2048] reuses it
//   R1 [9437184, 17825792): wattnT [2304][2048] during GEMM1; attn [4096][2048] after
// xb (bf16 of x, [4096][2048]) lives in the FIRST HALF OF d_out (33.5MB f32
// buffer, dead until GEMM2) -> zero workspace growth.
// ---------------------------------------------------------------------------
extern "C" void kernel_launch(void* const* d_in, const int* in_sizes, int n_in,
                              void* d_out, int out_size, void* d_ws, size_t ws_size,
                              hipStream_t stream)
{
    const float* x     = (const float*)d_in[0];   // [2,2048,2048] f32 = [4096][2048]
    const float* wattn = (const float*)d_in[1];   // [2048][2304] f32
    const float* wout  = (const float*)d_in[2];   // [2048][2048] f32
    float* out = (float*)d_out;                   // [4096][2048] f32

    unsigned short* ws = (unsigned short*)d_ws;
    unsigned short* qkv    = ws;                        // R0
    unsigned short* woutT  = ws;                        // R0 (after mqa)
    unsigned short* wattnT = ws + (size_t)9437184;      // R1
    unsigned short* attn   = ws + (size_t)9437184;      // R1 (after GEMM1)
    unsigned short* xb     = (unsigned short*)d_out;    // scratch until GEMM2

    // 0) xb = bf16(x)  (all-async bf16 GEMM path everywhere)
    cvt_bf16<<<dim3(4096), 256, 0, stream>>>(x, xb);
    // 1) wattnT[n][k] = bf16(w_attn[k][n])
    transpose_cvt<<<dim3(2304 / 64, 2048 / 64), 256, 0, stream>>>(wattn, wattnT, 2048, 2304);
    // 2) qkv = xb @ w_attn   (both operands async bf16, out bf16)
    gemm_bt<false><<<dim3(2304 / 128, 4096 / 128), 256, 0, stream>>>(
        xb, wattnT, qkv, 4096, 2304, 2048);
    // 3) flash MQA (overwrites wattnT region with attn)
    mqa_flash<<<dim3(2 * 16 * 16), 256, 0, stream>>>(qkv, attn);
    // 4) woutT[n][k] = bf16(w_out[k][n])  (into dead qkv region)
    transpose_cvt<<<dim3(2048 / 64, 2048 / 64), 256, 0, stream>>>(wout, woutT, 2048, 2048);
    // 5) out = attn @ w_out  (xb region of d_out overwritten here — xb is dead)
    gemm_bt<true><<<dim3(2048 / 128, 4096 / 128), 256, 0, stream>>>(
        attn, woutT, out, 4096, 2048, 2048);
}

// Round 10
// 285.880 us; speedup vs baseline: 1.0126x; 1.0126x over previous
//
#include <hip/hip_runtime.h>
#include <hip/hip_bf16.h>

typedef __attribute__((ext_vector_type(8))) short short8;
typedef __attribute__((ext_vector_type(4))) float f32x4;

#define GLOBAL_AS __attribute__((address_space(1)))
#define LDS_AS    __attribute__((address_space(3)))

__device__ __forceinline__ unsigned short f2bf(float f) {
    union { float f; unsigned int u; } v; v.f = f;
    unsigned int r = v.u + 0x7FFFu + ((v.u >> 16) & 1u);  // RNE
    return (unsigned short)(r >> 16);
}

// packed f32x2 -> bf16x2 (v_cvt_pk_bf16_f32 on gfx950), RNE
__device__ __forceinline__ unsigned int pk_bf16(float a, float b) {
    union { __hip_bfloat162 h; unsigned int u; } c;
    c.h = __float22bfloat162_rn(float2{a, b});
    return c.u;
}

__device__ __forceinline__ short8 cvt8v(float4 a, float4 b) {
    union { short8 s; unsigned int u[4]; } c;
    c.u[0] = pk_bf16(a.x, a.y); c.u[1] = pk_bf16(a.z, a.w);
    c.u[2] = pk_bf16(b.x, b.y); c.u[3] = pk_bf16(b.z, b.w);
    return c.s;
}

// async global->LDS, 16B per lane; lds base wave-uniform, lane i lands at +i*16
__device__ __forceinline__ void async_ld16(const unsigned short* g, unsigned short* l) {
    __builtin_amdgcn_global_load_lds((const GLOBAL_AS unsigned int*)g,
                                     (LDS_AS unsigned int*)l, 16, 0, 0);
}

// counted vmcnt wait + raw barrier (T4): never drain the prefetch queue
#define WAITV(N) asm volatile("s_waitcnt vmcnt(" #N ")" ::: "memory")
#define BARSYNC() do { __builtin_amdgcn_s_barrier(); __builtin_amdgcn_sched_barrier(0); } while (0)

// ---------------------------------------------------------------------------
// Elementwise f32 -> bf16 (RNE). 8 elems/thread.
// ---------------------------------------------------------------------------
__global__ __launch_bounds__(256) void cvt_bf16(
    const float* __restrict__ src, unsigned short* __restrict__ dst)
{
    const size_t i = ((size_t)blockIdx.x * 256 + threadIdx.x) * 8;
    float4 a = *(const float4*)(src + i);
    float4 b = *(const float4*)(src + i + 4);
    *(short8*)(dst + i) = cvt8v(a, b);
}

// ---------------------------------------------------------------------------
// Transpose+convert: dst[n][k] bf16 = src[k][n] f32. Grid (N/64, K/64).
// ---------------------------------------------------------------------------
__global__ __launch_bounds__(256) void transpose_cvt(
    const float* __restrict__ src, unsigned short* __restrict__ dst, int K, int N)
{
    __shared__ unsigned short t[64][72];
    const int tid = threadIdx.x;
    const int n0 = blockIdx.x * 64, k0 = blockIdx.y * 64;
    #pragma unroll
    for (int it = 0; it < 4; ++it) {
        int r = it * 16 + (tid >> 4);
        int c = (tid & 15) * 4;
        float4 v = *(const float4*)(src + (size_t)(k0 + r) * N + n0 + c);
        t[r][c] = f2bf(v.x); t[r][c + 1] = f2bf(v.y);
        t[r][c + 2] = f2bf(v.z); t[r][c + 3] = f2bf(v.w);
    }
    __syncthreads();
    const int nr = tid >> 2, kg = (tid & 3) * 16;
    short8 o0, o1;
    #pragma unroll
    for (int j = 0; j < 8; ++j) { o0[j] = (short)t[kg + j][nr]; o1[j] = (short)t[kg + 8 + j][nr]; }
    *(short8*)(dst + (size_t)(n0 + nr) * K + k0 + kg) = o0;
    *(short8*)(dst + (size_t)(n0 + nr) * K + k0 + kg + 8) = o1;
}

// ---------------------------------------------------------------------------
// GEMM v8: 128x128 tile, BK=32, quad-buffered counted-vmcnt (r9 skeleton),
// now with 512 THREADS / 8 WAVES per block, each wave owning 64x32 (acc 4x2).
// Rationale: r6/r8/r9 (three different pipeline structures, all 8 waves/CU)
// were indistinguishable at ~84us/GEMM. m102's shape curve says the m97-class
// structure's TF tracks co-resident waves: 1 blk/CU->320, 2->~460 (us),
// 4->833 TF. Grid caps blocks/CU at 2, so double waves/BLOCK instead:
// 16 waves/CU = 4/SIMD. Per-CU MFMA work unchanged; per-wave staging halves
// (2 gload_lds/tile -> body WAITV(4), tail 4,4,2,0 — flight still 3 tiles).
// Bank swizzle + XCD chunk swizzle unchanged (verified rounds 5-9).
// LDS 64KB -> 2 blocks/CU; lb(512,4) = 4 waves/EU = 2 blocks/CU, VGPR<=128.
// ---------------------------------------------------------------------------
__device__ __forceinline__ void stage_tile(
    const unsigned short* __restrict__ Ag, const unsigned short* __restrict__ Bg,
    unsigned short (*Asb)[32], unsigned short (*Bsb)[32],
    int m0, int n0, int K, int k, int w, int srow, int scol)
{
    async_ld16(Ag + (size_t)(m0 + w * 16 + srow) * K + k + scol, &Asb[w * 16][0]);
    async_ld16(Bg + (size_t)(n0 + w * 16 + srow) * K + k + scol, &Bsb[w * 16][0]);
}

__device__ __forceinline__ void compute_tile(
    const unsigned short (*Asb)[32], const unsigned short (*Bsb)[32],
    int rw, int cw, int l15, int quad, f32x4 acc[4][2])
{
    const int pc = (quad ^ (l15 & 3)) * 8;   // read-side swizzled chunk
    short8 af[4], bf[2];
    #pragma unroll
    for (int i = 0; i < 4; ++i)
        af[i] = *(const short8*)&Asb[rw + i * 16 + l15][pc];
    #pragma unroll
    for (int j = 0; j < 2; ++j)
        bf[j] = *(const short8*)&Bsb[cw + j * 16 + l15][pc];
    #pragma unroll
    for (int i = 0; i < 4; ++i)
        #pragma unroll
        for (int j = 0; j < 2; ++j)
            acc[i][j] = __builtin_amdgcn_mfma_f32_16x16x32_bf16(af[i], bf[j], acc[i][j], 0, 0, 0);
}

template<bool OUT_F32>
__global__ __launch_bounds__(512, 4) void gemm_bt(
    const unsigned short* __restrict__ Ab, const unsigned short* __restrict__ Bt,
    void* __restrict__ Cv, int M, int N, int K)   // requires K % 128 == 0
{
    __shared__ __align__(16) unsigned short As0[128][32], Bs0[128][32];
    __shared__ __align__(16) unsigned short As1[128][32], Bs1[128][32];
    __shared__ __align__(16) unsigned short As2[128][32], Bs2[128][32];
    __shared__ __align__(16) unsigned short As3[128][32], Bs3[128][32];

    const int tid = threadIdx.x, lane = tid & 63, w = tid >> 6;   // w: 0..7
    const int quad = lane >> 4, l15 = lane & 15;

    // XCD-chunked bijective swizzle (nwg % 8 == 0 for both GEMM grids)
    const int nwg = gridDim.x * gridDim.y;
    int lin = blockIdx.y * gridDim.x + blockIdx.x;
    lin = (lin & 7) * (nwg >> 3) + (lin >> 3);
    const int m0 = (lin / gridDim.x) * 128, n0 = (lin % gridDim.x) * 128;

    // wave (wr, wc): rows wr*64..+63, cols wc*32..+31
    const int rw = (w >> 2) * 64, cw = (w & 3) * 32;

    const f32x4 zero = {0.f, 0.f, 0.f, 0.f};
    f32x4 acc[4][2];
    #pragma unroll
    for (int i = 0; i < 4; ++i) { acc[i][0] = zero; acc[i][1] = zero; }

    // staging map (per wave, 64 lanes): 4 lanes/row over 16 rows, 16B/lane,
    // chunk XOR'd by row&3 (write-side of the bank-swizzle involution)
    const int srow = lane >> 2;                              // 0..15
    const int scol = (((lane & 3) ^ (srow & 3)) * 8);

    // -------- prologue: tiles 0,1,2 -> buf0,1,2 (6 loads/wave) --------
    stage_tile(Ab, Bt, As0, Bs0, m0, n0, K, 0,  w, srow, scol);
    stage_tile(Ab, Bt, As1, Bs1, m0, n0, K, 32, w, srow, scol);
    stage_tile(Ab, Bt, As2, Bs2, m0, n0, K, 64, w, srow, scol);

    // -------- body: 4 tiles per iteration; last 4 tiles peeled --------
    for (int k0 = 0; k0 + 224 < K; k0 += 128) {
        WAITV(4); BARSYNC();
        stage_tile(Ab, Bt, As3, Bs3, m0, n0, K, k0 + 96, w, srow, scol);
        compute_tile(As0, Bs0, rw, cw, l15, quad, acc);

        WAITV(4); BARSYNC();
        stage_tile(Ab, Bt, As0, Bs0, m0, n0, K, k0 + 128, w, srow, scol);
        compute_tile(As1, Bs1, rw, cw, l15, quad, acc);

        WAITV(4); BARSYNC();
        stage_tile(Ab, Bt, As1, Bs1, m0, n0, K, k0 + 160, w, srow, scol);
        compute_tile(As2, Bs2, rw, cw, l15, quad, acc);

        WAITV(4); BARSYNC();
        stage_tile(Ab, Bt, As2, Bs2, m0, n0, K, k0 + 192, w, srow, scol);
        compute_tile(As3, Bs3, rw, cw, l15, quad, acc);
    }

    // -------- tail: last 4 tiles (bufs 0..3); waits 4,4,2,0 ----
    {
        const int kt = K - 128;
        WAITV(4); BARSYNC();
        stage_tile(Ab, Bt, As3, Bs3, m0, n0, K, kt + 96, w, srow, scol);
        compute_tile(As0, Bs0, rw, cw, l15, quad, acc);

        WAITV(4); BARSYNC();
        compute_tile(As1, Bs1, rw, cw, l15, quad, acc);

        WAITV(2); BARSYNC();
        compute_tile(As2, Bs2, rw, cw, l15, quad, acc);

        WAITV(0); BARSYNC();
        compute_tile(As3, Bs3, rw, cw, l15, quad, acc);
    }

    #pragma unroll
    for (int i = 0; i < 4; ++i) {
        const int row = m0 + rw + i * 16 + quad * 4;
        #pragma unroll
        for (int j = 0; j < 2; ++j) {
            const int col = n0 + cw + j * 16 + l15;
            #pragma unroll
            for (int r = 0; r < 4; ++r) {
                if constexpr (OUT_F32)
                    ((float*)Cv)[(size_t)(row + r) * N + col] = acc[i][j][r];
                else
                    ((unsigned short*)Cv)[(size_t)(row + r) * N + col] = f2bf(acc[i][j][r]);
            }
        }
    }
}

// ---------------------------------------------------------------------------
// Flash MQA v6 (unchanged — proven): swapped-operand QK^T with in-register P
// pack into the PV B-fragment; K/V double-buffered, one barrier per
// iteration; O^T epilogue transpose through LDS; fixed-max softmax M=12;
// denominator via ones rows 128..143 of VT.
// ---------------------------------------------------------------------------
__global__ __launch_bounds__(256) void mqa_flash(
    const unsigned short* __restrict__ qkv,  // [B*S, 2304] bf16
    unsigned short* __restrict__ attn)       // [B*S, 2048] bf16
{
    const int S = 2048, QKVW = 2304;
    __shared__ __align__(16) union {
        struct {
            unsigned short Ks[2][32][136];   // [buf][permuted key][d]
            unsigned short VT[2][144][44];   // [buf][d][key]; rows 128..143 ones
        } s;
        unsigned short T[4][32][136];        // epilogue per-wave O transpose
    } sm;

    const int tid = threadIdx.x, lane = tid & 63, w = tid >> 6;
    const int quad = lane >> 4, l15 = lane & 15;
    const int bid = blockIdx.x;
    const int qb = bid & 15;          // 16 q-blocks of 128 rows
    const int h  = (bid >> 4) & 15;
    const int b  = bid >> 8;

    // ones rows for the denominator, both buffers (cols 0..31 are read)
    for (int i = tid; i < 2 * 16 * 32; i += 256)
        sm.s.VT[i >> 9][128 + ((i >> 5) & 15)][i & 31] = 0x3F80;

    const unsigned short* base = qkv + (size_t)b * S * QKVW;

    // Q fragments (QK B-operand: n=q=l15, k=quad*8+j — same layout as A-frag)
    short8 qf[2][4];
    #pragma unroll
    for (int sub = 0; sub < 2; ++sub) {
        const int row = qb * 128 + w * 32 + sub * 16 + l15;
        #pragma unroll
        for (int ds = 0; ds < 4; ++ds)
            qf[sub][ds] = *(const short8*)(base + (size_t)row * QKVW + h * 128 + ds * 32 + quad * 8);
    }

    const f32x4 zero = {0.f, 0.f, 0.f, 0.f};
    f32x4 o[2][9];                      // O^T: o[sub][dsub][r] = O[d=dsub*16+quad*4+r][q=l15]
    #pragma unroll
    for (int sub = 0; sub < 2; ++sub)
        #pragma unroll
        for (int d = 0; d < 9; ++d) o[sub][d] = zero;

    // staging maps
    const int krow = tid & 31, kdg = tid >> 5;            // K: key, 16-d group
    const int kpr  = ((krow & 1) << 4) | (krow >> 1);     // even/odd permuted row
    const int vkp  = tid & 15, vdg = tid >> 4;            // V: key pair, 8-d group

    const unsigned short* kp = base + (size_t)krow * QKVW + 2048 + kdg * 16;
    const unsigned short* vp = base + (size_t)(2 * vkp) * QKVW + 2176 + vdg * 8;

    // prologue: tile 0 into regs
    short8 k0v = *(const short8*)kp;
    short8 k1v = *(const short8*)(kp + 8);
    short8 v0v = *(const short8*)vp;
    short8 v1v = *(const short8*)(vp + QKVW);

    for (int kb = 0; kb < S; kb += 32) {
        const int p = (kb >> 5) & 1;

        // write tile kb into buf[p] (compiler inserts the vmcnt wait; loads
        // were issued one iteration ago, so it's cheap). Prior readers of
        // buf[p] (iter kb-2) are fenced by iter kb-1's barrier.
        *(short8*)(&sm.s.Ks[p][kpr][kdg * 16]) = k0v;
        *(short8*)(&sm.s.Ks[p][kpr][kdg * 16 + 8]) = k1v;
        #pragma unroll
        for (int j = 0; j < 8; ++j) {
            unsigned int pkv = (unsigned int)(unsigned short)v0v[j]
                             | ((unsigned int)(unsigned short)v1v[j] << 16);
            *(unsigned int*)(&sm.s.VT[p][vdg * 8 + j][vkp * 2]) = pkv;
        }

        // issue next tile loads (waited at the TOP of the next iteration:
        // latency hides under the barrier + full compute phase below)
        if (kb + 32 < S) {
            kp += 32 * QKVW; vp += 32 * QKVW;
            k0v = *(const short8*)kp;
            k1v = *(const short8*)(kp + 8);
            v0v = *(const short8*)vp;
            v1v = *(const short8*)(vp + QKVW);
        }

        __syncthreads();   // single barrier per iteration (double-buffered)

        __builtin_amdgcn_s_setprio(1);

        // --- QK^T swapped: sc[sub][par] = mfma(K_par, Q_sub) -> S[key][q];
        //     lane holds S[key = 8*quad + 2r + par][q = l15] ---
        f32x4 sc[2][2];
        sc[0][0] = zero; sc[0][1] = zero; sc[1][0] = zero; sc[1][1] = zero;
        #pragma unroll
        for (int ds = 0; ds < 4; ++ds) {
            short8 kf0 = *(const short8*)(&sm.s.Ks[p][l15][ds * 32 + quad * 8]);      // even keys
            short8 kf1 = *(const short8*)(&sm.s.Ks[p][16 + l15][ds * 32 + quad * 8]); // odd keys
            #pragma unroll
            for (int sub = 0; sub < 2; ++sub) {
                sc[sub][0] = __builtin_amdgcn_mfma_f32_16x16x32_bf16(kf0, qf[sub][ds], sc[sub][0], 0, 0, 0);
                sc[sub][1] = __builtin_amdgcn_mfma_f32_16x16x32_bf16(kf1, qf[sub][ds], sc[sub][1], 0, 0, 0);
            }
        }

        // --- exp + in-register P pack: u[r] = (key 8q+2r, key 8q+2r+1) ->
        //     exactly the PV B-fragment (k=quad*8+j, n=q=l15). No LDS. ---
        const float scale = 0.08838834764831845f;  // 128^-0.5
        short8 pf[2];
        #pragma unroll
        for (int sub = 0; sub < 2; ++sub) {
            union { short8 sv; unsigned int u[4]; } c;
            #pragma unroll
            for (int r = 0; r < 4; ++r) {
                float e0 = __expf(fmaf(sc[sub][0][r], scale, -12.f));
                float e1 = __expf(fmaf(sc[sub][1][r], scale, -12.f));
                c.u[r] = pk_bf16(e0, e1);
            }
            pf[sub] = c.sv;
        }

        // --- PV: o^T = mfma(V^T, P); V-frags read once, used for both subs ---
        #pragma unroll
        for (int dsub = 0; dsub < 9; ++dsub) {
            short8 vf = *(const short8*)(&sm.s.VT[p][dsub * 16 + l15][quad * 8]);
            o[0][dsub] = __builtin_amdgcn_mfma_f32_16x16x32_bf16(vf, pf[0], o[0][dsub], 0, 0, 0);
            o[1][dsub] = __builtin_amdgcn_mfma_f32_16x16x32_bf16(vf, pf[1], o[1][dsub], 0, 0, 0);
        }

        __builtin_amdgcn_s_setprio(0);
    }

    __syncthreads();   // all compute reads of K/V buffers done before overlay

    // epilogue: per-wave O^T -> O transpose through LDS, then coalesced store.
    // den = o[sub][8] (ones-rows MFMA) is uniform across quad/r: inv per q=l15.
    #pragma unroll
    for (int sub = 0; sub < 2; ++sub) {
        const float inv = 1.0f / o[sub][8][0];
        #pragma unroll
        for (int dsub = 0; dsub < 8; ++dsub) {
            unsigned int lo = pk_bf16(o[sub][dsub][0] * inv, o[sub][dsub][1] * inv);
            unsigned int hi = pk_bf16(o[sub][dsub][2] * inv, o[sub][dsub][3] * inv);
            unsigned int* dst = (unsigned int*)&sm.T[w][sub * 16 + l15][dsub * 16 + quad * 4];
            dst[0] = lo; dst[1] = hi;
        }
    }
    __syncthreads();

    const size_t rowbase = (size_t)b * S + qb * 128 + w * 32;
    #pragma unroll
    for (int pass = 0; pass < 8; ++pass) {
        const int row = pass * 4 + quad;
        short8 ov = *(const short8*)(&sm.T[w][row][l15 * 8]);
        *(short8*)(&attn[(rowbase + row) * 2048 + h * 128 + l15 * 8]) = ov;
    }
}

// ---------------------------------------------------------------------------
// ws layout (ushort units), total 35.65 MB (proven-safe footprint):
//   R0 [0, 9437184): qkv bf16 [4096][2304]; after mqa, woutT [2048][2048] reuses it
//   R1 [9437184, 17825792): wattnT [2304][2048] during GEMM1; attn [4096][2048] after
// xb (bf16 of x, [4096][2048]) lives in the FIRST HALF OF d_out (33.5MB f32
// buffer, dead until GEMM2) -> zero workspace growth.
// ---------------------------------------------------------------------------
extern "C" void kernel_launch(void* const* d_in, const int* in_sizes, int n_in,
                              void* d_out, int out_size, void* d_ws, size_t ws_size,
                              hipStream_t stream)
{
    const float* x     = (const float*)d_in[0];   // [2,2048,2048] f32 = [4096][2048]
    const float* wattn = (const float*)d_in[1];   // [2048][2304] f32
    const float* wout  = (const float*)d_in[2];   // [2048][2048] f32
    float* out = (float*)d_out;                   // [4096][2048] f32

    unsigned short* ws = (unsigned short*)d_ws;
    unsigned short* qkv    = ws;                        // R0
    unsigned short* woutT  = ws;                        // R0 (after mqa)
    unsigned short* wattnT = ws + (size_t)9437184;      // R1
    unsigned short* attn   = ws + (size_t)9437184;      // R1 (after GEMM1)
    unsigned short* xb     = (unsigned short*)d_out;    // scratch until GEMM2

    // 0) xb = bf16(x)  (all-async bf16 GEMM path everywhere)
    cvt_bf16<<<dim3(4096), 256, 0, stream>>>(x, xb);
    // 1) wattnT[n][k] = bf16(w_attn[k][n])
    transpose_cvt<<<dim3(2304 / 64, 2048 / 64), 256, 0, stream>>>(wattn, wattnT, 2048, 2304);
    // 2) qkv = xb @ w_attn   (both operands async bf16, out bf16)
    gemm_bt<false><<<dim3(2304 / 128, 4096 / 128), 512, 0, stream>>>(
        xb, wattnT, qkv, 4096, 2304, 2048);
    // 3) flash MQA (overwrites wattnT region with attn)
    mqa_flash<<<dim3(2 * 16 * 16), 256, 0, stream>>>(qkv, attn);
    // 4) woutT[n][k] = bf16(w_out[k][n])  (into dead qkv region)
    transpose_cvt<<<dim3(2048 / 64, 2048 / 64), 256, 0, stream>>>(wout, woutT, 2048, 2048);
    // 5) out = attn @ w_out  (xb region of d_out overwritten here — xb is dead)
    gemm_bt<true><<<dim3(2048 / 128, 4096 / 128), 512, 0, stream>>>(
        attn, woutT, out, 4096, 2048, 2048);
}

// Round 11
// 280.716 us; speedup vs baseline: 1.0312x; 1.0184x over previous
//
#include <hip/hip_runtime.h>
#include <hip/hip_bf16.h>

typedef __attribute__((ext_vector_type(8))) short short8;
typedef __attribute__((ext_vector_type(4))) float f32x4;

#define GLOBAL_AS __attribute__((address_space(1)))
#define LDS_AS    __attribute__((address_space(3)))

__device__ __forceinline__ unsigned short f2bf(float f) {
    union { float f; unsigned int u; } v; v.f = f;
    unsigned int r = v.u + 0x7FFFu + ((v.u >> 16) & 1u);  // RNE
    return (unsigned short)(r >> 16);
}

// packed f32x2 -> bf16x2 (v_cvt_pk_bf16_f32 on gfx950), RNE
__device__ __forceinline__ unsigned int pk_bf16(float a, float b) {
    union { __hip_bfloat162 h; unsigned int u; } c;
    c.h = __float22bfloat162_rn(float2{a, b});
    return c.u;
}

__device__ __forceinline__ short8 cvt8v(float4 a, float4 b) {
    union { short8 s; unsigned int u[4]; } c;
    c.u[0] = pk_bf16(a.x, a.y); c.u[1] = pk_bf16(a.z, a.w);
    c.u[2] = pk_bf16(b.x, b.y); c.u[3] = pk_bf16(b.z, b.w);
    return c.s;
}

// async global->LDS, 16B per lane; lds base wave-uniform, lane i lands at +i*16
__device__ __forceinline__ void async_ld16(const unsigned short* g, unsigned short* l) {
    __builtin_amdgcn_global_load_lds((const GLOBAL_AS unsigned int*)g,
                                     (LDS_AS unsigned int*)l, 16, 0, 0);
}

// ---------------------------------------------------------------------------
// Elementwise f32 -> bf16 (RNE). 8 elems/thread.
// ---------------------------------------------------------------------------
__global__ __launch_bounds__(256) void cvt_bf16(
    const float* __restrict__ src, unsigned short* __restrict__ dst)
{
    const size_t i = ((size_t)blockIdx.x * 256 + threadIdx.x) * 8;
    float4 a = *(const float4*)(src + i);
    float4 b = *(const float4*)(src + i + 4);
    *(short8*)(dst + i) = cvt8v(a, b);
}

// ---------------------------------------------------------------------------
// Transpose+convert: dst[n][k] bf16 = src[k][n] f32. Grid (N/64, K/64).
// ---------------------------------------------------------------------------
__global__ __launch_bounds__(256) void transpose_cvt(
    const float* __restrict__ src, unsigned short* __restrict__ dst, int K, int N)
{
    __shared__ unsigned short t[64][72];
    const int tid = threadIdx.x;
    const int n0 = blockIdx.x * 64, k0 = blockIdx.y * 64;
    #pragma unroll
    for (int it = 0; it < 4; ++it) {
        int r = it * 16 + (tid >> 4);
        int c = (tid & 15) * 4;
        float4 v = *(const float4*)(src + (size_t)(k0 + r) * N + n0 + c);
        t[r][c] = f2bf(v.x); t[r][c + 1] = f2bf(v.y);
        t[r][c + 2] = f2bf(v.z); t[r][c + 3] = f2bf(v.w);
    }
    __syncthreads();
    const int nr = tid >> 2, kg = (tid & 3) * 16;
    short8 o0, o1;
    #pragma unroll
    for (int j = 0; j < 8; ++j) { o0[j] = (short)t[kg + j][nr]; o1[j] = (short)t[kg + 8 + j][nr]; }
    *(short8*)(dst + (size_t)(n0 + nr) * K + k0 + kg) = o0;
    *(short8*)(dst + (size_t)(n0 + nr) * K + k0 + kg + 8) = o1;
}

// ---------------------------------------------------------------------------
// GEMM (round-6 exact revert — best measured config, 277.8us total):
// 128x128 tile, BK=64, single-buffered, 2 barriers/step, all-async bf16.
// Rounds 7-10 falsified every pipeline variant (disjoint dbuf, counted
// vmcnt quad-buffer, 8-wave blocks): all ~84us/GEMM. The stall interleaving
// is block-level (2 blocks/CU grid cap), not intra-block schedule.
//  - XCD-chunked bijective swizzle (FETCH 175->80MB, round 5).
//  - Both-sides XOR bank swizzle (verified rounds 6-8).
// ---------------------------------------------------------------------------
template<bool OUT_F32>
__global__ __launch_bounds__(256, 3) void gemm_bt(
    const unsigned short* __restrict__ Ab, const unsigned short* __restrict__ Bt,
    void* __restrict__ Cv, int M, int N, int K)
{
    __shared__ __align__(16) unsigned short As[128][64];
    __shared__ __align__(16) unsigned short Bs[128][64];

    const int tid = threadIdx.x, lane = tid & 63, w = tid >> 6;
    const int quad = lane >> 4, l15 = lane & 15;

    // XCD-chunked bijective swizzle (nwg % 8 == 0 for both GEMM grids)
    const int nwg = gridDim.x * gridDim.y;
    int lin = blockIdx.y * gridDim.x + blockIdx.x;
    lin = (lin & 7) * (nwg >> 3) + (lin >> 3);
    const int m0 = (lin / gridDim.x) * 128, n0 = (lin % gridDim.x) * 128;

    const int rw = (w >> 1) * 64, cw = (w & 1) * 64;   // wave's output quadrant

    const f32x4 zero = {0.f, 0.f, 0.f, 0.f};
    f32x4 acc[4][4];
    #pragma unroll
    for (int i = 0; i < 4; ++i)
        #pragma unroll
        for (int j = 0; j < 4; ++j) acc[i][j] = zero;

    // staging map: 8 lanes/row, 16B/lane; chunk permuted by srow for the
    // LDS XOR swizzle (lane fetches logical chunk (lane&7)^srow)
    const int srow = lane >> 3;
    const int scol = ((lane & 7) ^ srow) * 8;

    const unsigned short* Asf = &As[0][0];
    const unsigned short* Bsf = &Bs[0][0];
    const int rx = (l15 & 7) << 3;     // read-side swizzle XOR (ushort units)

    // -------- prologue: stage tile 0 --------
    #pragma unroll
    for (int c = 0; c < 4; ++c)
        async_ld16(Ab + (size_t)(m0 + w * 32 + c * 8 + srow) * K + scol,
                   &As[w * 32 + c * 8][0]);
    #pragma unroll
    for (int c = 0; c < 4; ++c)
        async_ld16(Bt + (size_t)(n0 + w * 32 + c * 8 + srow) * K + scol,
                   &Bs[w * 32 + c * 8][0]);

    for (int k0 = 0; k0 < K; k0 += 64) {
        __syncthreads();   // drain: async(k) landed, tile k visible

        short8 af[4][2], bf2[4][2];
        #pragma unroll
        for (int i = 0; i < 4; ++i) {
            const int rb = (rw + i * 16 + l15) * 64;
            af[i][0] = *(const short8*)(Asf + ((rb + quad * 8) ^ rx));
            af[i][1] = *(const short8*)(Asf + ((rb + 32 + quad * 8) ^ rx));
        }
        #pragma unroll
        for (int j = 0; j < 4; ++j) {
            const int rb = (cw + j * 16 + l15) * 64;
            bf2[j][0] = *(const short8*)(Bsf + ((rb + quad * 8) ^ rx));
            bf2[j][1] = *(const short8*)(Bsf + ((rb + 32 + quad * 8) ^ rx));
        }
        __syncthreads();   // all waves done reading LDS tile k

        if (k0 + 64 < K) {
            #pragma unroll
            for (int c = 0; c < 4; ++c)
                async_ld16(Ab + (size_t)(m0 + w * 32 + c * 8 + srow) * K + k0 + 64 + scol,
                           &As[w * 32 + c * 8][0]);
            #pragma unroll
            for (int c = 0; c < 4; ++c)
                async_ld16(Bt + (size_t)(n0 + w * 32 + c * 8 + srow) * K + k0 + 64 + scol,
                           &Bs[w * 32 + c * 8][0]);
        }

        #pragma unroll
        for (int i = 0; i < 4; ++i)
            #pragma unroll
            for (int j = 0; j < 4; ++j) {
                acc[i][j] = __builtin_amdgcn_mfma_f32_16x16x32_bf16(af[i][0], bf2[j][0], acc[i][j], 0, 0, 0);
                acc[i][j] = __builtin_amdgcn_mfma_f32_16x16x32_bf16(af[i][1], bf2[j][1], acc[i][j], 0, 0, 0);
            }
    }

    #pragma unroll
    for (int i = 0; i < 4; ++i) {
        const int row = m0 + rw + i * 16 + quad * 4;
        #pragma unroll
        for (int j = 0; j < 4; ++j) {
            const int col = n0 + cw + j * 16 + l15;
            #pragma unroll
            for (int r = 0; r < 4; ++r) {
                if constexpr (OUT_F32)
                    ((float*)Cv)[(size_t)(row + r) * N + col] = acc[i][j][r];
                else
                    ((unsigned short*)Cv)[(size_t)(row + r) * N + col] = f2bf(acc[i][j][r]);
            }
        }
    }
}

// ---------------------------------------------------------------------------
// Flash MQA v7: KVBLK=64 (was 32). Counters (r6-r10): MfmaUtil 35%, VALU 46%,
// wall ~1650cy/block-iter vs ~1100cy issued work -> ~33% per-iteration fixed
// cost (barrier rendezvous, stage issue, vmcnt turnaround, setprio, loop
// arith) paid 64x. KVBLK=64 halves every fixed cost (32 iters), keeps all
// per-key work identical, and doubles independent MFMA/exp batch sizes.
// Structure per 64-key tile: two 32-key groups, each handled exactly like
// the proven v6 path (even/odd key permutation per group, swapped QK^T,
// in-register P pack, denominator via ones rows). LDS 74.5KB -> still
// 2 blocks/CU (grid caps at 2 anyway).
// ---------------------------------------------------------------------------
__global__ __launch_bounds__(256) void mqa_flash(
    const unsigned short* __restrict__ qkv,  // [B*S, 2304] bf16
    unsigned short* __restrict__ attn)       // [B*S, 2048] bf16
{
    const int S = 2048, QKVW = 2304;
    __shared__ __align__(16) union {
        struct {
            unsigned short Ks[2][64][136];   // [buf][group*32 + permuted key][d]
            unsigned short VT[2][144][72];   // [buf][d][key 0..63]; rows 128..143 ones
        } s;
        unsigned short T[4][32][136];        // epilogue per-wave O transpose
    } sm;

    const int tid = threadIdx.x, lane = tid & 63, w = tid >> 6;
    const int quad = lane >> 4, l15 = lane & 15;
    const int bid = blockIdx.x;
    const int qb = bid & 15;          // 16 q-blocks of 128 rows
    const int h  = (bid >> 4) & 15;
    const int b  = bid >> 8;

    // ones rows for the denominator, both buffers, cols 0..63
    for (int i = tid; i < 2 * 16 * 64; i += 256)
        sm.s.VT[i >> 10][128 + ((i >> 6) & 15)][i & 63] = 0x3F80;

    const unsigned short* base = qkv + (size_t)b * S * QKVW;

    // Q fragments (QK B-operand: n=q=l15, k=quad*8+j)
    short8 qf[2][4];
    #pragma unroll
    for (int sub = 0; sub < 2; ++sub) {
        const int row = qb * 128 + w * 32 + sub * 16 + l15;
        #pragma unroll
        for (int ds = 0; ds < 4; ++ds)
            qf[sub][ds] = *(const short8*)(base + (size_t)row * QKVW + h * 128 + ds * 32 + quad * 8);
    }

    const f32x4 zero = {0.f, 0.f, 0.f, 0.f};
    f32x4 o[2][9];                      // O^T: o[sub][dsub][r] = O[d=dsub*16+quad*4+r][q=l15]
    #pragma unroll
    for (int sub = 0; sub < 2; ++sub)
        #pragma unroll
        for (int d = 0; d < 9; ++d) o[sub][d] = zero;

    // staging maps (256 threads cover 64 keys x 128 d)
    const int krow = tid & 63, kdg = tid >> 6;            // K: key, 32-ushort d-group
    const int kk = krow & 31;
    const int kpr = (krow & 32) + (((kk & 1) << 4) | (kk >> 1));  // per-group even/odd perm
    const int vkp = tid & 31, vdg = tid >> 5;             // V: key pair, 16-d group

    const unsigned short* kp = base + (size_t)krow * QKVW + 2048 + kdg * 32;
    const unsigned short* vp = base + (size_t)(2 * vkp) * QKVW + 2176 + vdg * 16;

    // prologue: tile 0 into regs (K: 4x short8; V: 2 keys x 2x short8)
    short8 k0v = *(const short8*)kp;
    short8 k1v = *(const short8*)(kp + 8);
    short8 k2v = *(const short8*)(kp + 16);
    short8 k3v = *(const short8*)(kp + 24);
    short8 v0a = *(const short8*)vp;
    short8 v0b = *(const short8*)(vp + 8);
    short8 v1a = *(const short8*)(vp + QKVW);
    short8 v1b = *(const short8*)(vp + QKVW + 8);

    for (int kb = 0; kb < S; kb += 64) {
        const int p = (kb >> 6) & 1;

        // write tile kb into buf[p]; prior readers of buf[p] (iter kb-2)
        // are fenced by iter kb-1's barrier.
        *(short8*)(&sm.s.Ks[p][kpr][kdg * 32]) = k0v;
        *(short8*)(&sm.s.Ks[p][kpr][kdg * 32 + 8]) = k1v;
        *(short8*)(&sm.s.Ks[p][kpr][kdg * 32 + 16]) = k2v;
        *(short8*)(&sm.s.Ks[p][kpr][kdg * 32 + 24]) = k3v;
        #pragma unroll
        for (int j = 0; j < 8; ++j) {
            unsigned int pa = (unsigned int)(unsigned short)v0a[j]
                            | ((unsigned int)(unsigned short)v1a[j] << 16);
            unsigned int pb = (unsigned int)(unsigned short)v0b[j]
                            | ((unsigned int)(unsigned short)v1b[j] << 16);
            *(unsigned int*)(&sm.s.VT[p][vdg * 16 + j][vkp * 2]) = pa;
            *(unsigned int*)(&sm.s.VT[p][vdg * 16 + 8 + j][vkp * 2]) = pb;
        }

        // issue next tile loads (waited at the TOP of the next iteration)
        if (kb + 64 < S) {
            kp += 64 * QKVW; vp += 64 * QKVW;
            k0v = *(const short8*)kp;
            k1v = *(const short8*)(kp + 8);
            k2v = *(const short8*)(kp + 16);
            k3v = *(const short8*)(kp + 24);
            v0a = *(const short8*)vp;
            v0b = *(const short8*)(vp + 8);
            v1a = *(const short8*)(vp + QKVW);
            v1b = *(const short8*)(vp + QKVW + 8);
        }

        __syncthreads();   // single barrier per 64-key iteration

        __builtin_amdgcn_s_setprio(1);

        // --- QK^T swapped, 2 key-groups: sc[sub][g][par] = mfma(K,Q);
        //     lane holds S[key = g*32 + 8*quad + 2r + par][q = l15] ---
        f32x4 sc[2][2][2];
        #pragma unroll
        for (int sub = 0; sub < 2; ++sub)
            #pragma unroll
            for (int g = 0; g < 2; ++g) { sc[sub][g][0] = zero; sc[sub][g][1] = zero; }
        #pragma unroll
        for (int ds = 0; ds < 4; ++ds) {
            short8 kf[2][2];
            kf[0][0] = *(const short8*)(&sm.s.Ks[p][l15][ds * 32 + quad * 8]);
            kf[0][1] = *(const short8*)(&sm.s.Ks[p][16 + l15][ds * 32 + quad * 8]);
            kf[1][0] = *(const short8*)(&sm.s.Ks[p][32 + l15][ds * 32 + quad * 8]);
            kf[1][1] = *(const short8*)(&sm.s.Ks[p][48 + l15][ds * 32 + quad * 8]);
            #pragma unroll
            for (int sub = 0; sub < 2; ++sub)
                #pragma unroll
                for (int g = 0; g < 2; ++g) {
                    sc[sub][g][0] = __builtin_amdgcn_mfma_f32_16x16x32_bf16(kf[g][0], qf[sub][ds], sc[sub][g][0], 0, 0, 0);
                    sc[sub][g][1] = __builtin_amdgcn_mfma_f32_16x16x32_bf16(kf[g][1], qf[sub][ds], sc[sub][g][1], 0, 0, 0);
                }
        }

        // --- exp + in-register P pack per group -> PV B-fragments ---
        const float scale = 0.08838834764831845f;  // 128^-0.5
        short8 pf[2][2];
        #pragma unroll
        for (int sub = 0; sub < 2; ++sub)
            #pragma unroll
            for (int g = 0; g < 2; ++g) {
                union { short8 sv; unsigned int u[4]; } c;
                #pragma unroll
                for (int r = 0; r < 4; ++r) {
                    float e0 = __expf(fmaf(sc[sub][g][0][r], scale, -12.f));
                    float e1 = __expf(fmaf(sc[sub][g][1][r], scale, -12.f));
                    c.u[r] = pk_bf16(e0, e1);
                }
                pf[sub][g] = c.sv;
            }

        // --- PV: o^T += mfma(V^T_g, P_g), both groups ---
        #pragma unroll
        for (int dsub = 0; dsub < 9; ++dsub) {
            short8 vf0 = *(const short8*)(&sm.s.VT[p][dsub * 16 + l15][quad * 8]);
            short8 vf1 = *(const short8*)(&sm.s.VT[p][dsub * 16 + l15][32 + quad * 8]);
            o[0][dsub] = __builtin_amdgcn_mfma_f32_16x16x32_bf16(vf0, pf[0][0], o[0][dsub], 0, 0, 0);
            o[0][dsub] = __builtin_amdgcn_mfma_f32_16x16x32_bf16(vf1, pf[0][1], o[0][dsub], 0, 0, 0);
            o[1][dsub] = __builtin_amdgcn_mfma_f32_16x16x32_bf16(vf0, pf[1][0], o[1][dsub], 0, 0, 0);
            o[1][dsub] = __builtin_amdgcn_mfma_f32_16x16x32_bf16(vf1, pf[1][1], o[1][dsub], 0, 0, 0);
        }

        __builtin_amdgcn_s_setprio(0);
    }

    __syncthreads();   // all compute reads of K/V buffers done before overlay

    // epilogue: per-wave O^T -> O transpose through LDS, then coalesced store.
    // den = o[sub][8] (ones-rows MFMA) is uniform across quad/r: inv per q=l15.
    #pragma unroll
    for (int sub = 0; sub < 2; ++sub) {
        const float inv = 1.0f / o[sub][8][0];
        #pragma unroll
        for (int dsub = 0; dsub < 8; ++dsub) {
            unsigned int lo = pk_bf16(o[sub][dsub][0] * inv, o[sub][dsub][1] * inv);
            unsigned int hi = pk_bf16(o[sub][dsub][2] * inv, o[sub][dsub][3] * inv);
            unsigned int* dst = (unsigned int*)&sm.T[w][sub * 16 + l15][dsub * 16 + quad * 4];
            dst[0] = lo; dst[1] = hi;
        }
    }
    __syncthreads();

    const size_t rowbase = (size_t)b * S + qb * 128 + w * 32;
    #pragma unroll
    for (int pass = 0; pass < 8; ++pass) {
        const int row = pass * 4 + quad;
        short8 ov = *(const short8*)(&sm.T[w][row][l15 * 8]);
        *(short8*)(&attn[(rowbase + row) * 2048 + h * 128 + l15 * 8]) = ov;
    }
}

// ---------------------------------------------------------------------------
// ws layout (ushort units), total 35.65 MB (proven-safe footprint):
//   R0 [0, 9437184): qkv bf16 [4096][2304]; after mqa, woutT [2048][2048] reuses it
//   R1 [9437184, 17825792): wattnT [2304][2048] during GEMM1; attn [4096][2048] after
// xb (bf16 of x, [4096][2048]) lives in the FIRST HALF OF d_out (33.5MB f32
// buffer, dead until GEMM2) -> zero workspace growth.
// ---------------------------------------------------------------------------
extern "C" void kernel_launch(void* const* d_in, const int* in_sizes, int n_in,
                              void* d_out, int out_size, void* d_ws, size_t ws_size,
                              hipStream_t stream)
{
    const float* x     = (const float*)d_in[0];   // [2,2048,2048] f32 = [4096][2048]
    const float* wattn = (const float*)d_in[1];   // [2048][2304] f32
    const float* wout  = (const float*)d_in[2];   // [2048][2048] f32
    float* out = (float*)d_out;                   // [4096][2048] f32

    unsigned short* ws = (unsigned short*)d_ws;
    unsigned short* qkv    = ws;                        // R0
    unsigned short* woutT  = ws;                        // R0 (after mqa)
    unsigned short* wattnT = ws + (size_t)9437184;      // R1
    unsigned short* attn   = ws + (size_t)9437184;      // R1 (after GEMM1)
    unsigned short* xb     = (unsigned short*)d_out;    // scratch until GEMM2

    // 0) xb = bf16(x)  (all-async bf16 GEMM path everywhere)
    cvt_bf16<<<dim3(4096), 256, 0, stream>>>(x, xb);
    // 1) wattnT[n][k] = bf16(w_attn[k][n])
    transpose_cvt<<<dim3(2304 / 64, 2048 / 64), 256, 0, stream>>>(wattn, wattnT, 2048, 2304);
    // 2) qkv = xb @ w_attn   (both operands async bf16, out bf16)
    gemm_bt<false><<<dim3(2304 / 128, 4096 / 128), 256, 0, stream>>>(
        xb, wattnT, qkv, 4096, 2304, 2048);
    // 3) flash MQA (overwrites wattnT region with attn)
    mqa_flash<<<dim3(2 * 16 * 16), 256, 0, stream>>>(qkv, attn);
    // 4) woutT[n][k] = bf16(w_out[k][n])  (into dead qkv region)
    transpose_cvt<<<dim3(2048 / 64, 2048 / 64), 256, 0, stream>>>(wout, woutT, 2048, 2048);
    // 5) out = attn @ w_out  (xb region of d_out overwritten here — xb is dead)
    gemm_bt<true><<<dim3(2048 / 128, 4096 / 128), 256, 0, stream>>>(
        attn, woutT, out, 4096, 2048, 2048);
}

// Round 13
// 274.575 us; speedup vs baseline: 1.0543x; 1.0224x over previous
//
#include <hip/hip_runtime.h>
#include <hip/hip_bf16.h>

typedef __attribute__((ext_vector_type(8))) short short8;
typedef __attribute__((ext_vector_type(4))) float f32x4;

#define GLOBAL_AS __attribute__((address_space(1)))
#define LDS_AS    __attribute__((address_space(3)))

__device__ __forceinline__ unsigned short f2bf(float f) {
    union { float f; unsigned int u; } v; v.f = f;
    unsigned int r = v.u + 0x7FFFu + ((v.u >> 16) & 1u);  // RNE
    return (unsigned short)(r >> 16);
}

// packed f32x2 -> bf16x2 (v_cvt_pk_bf16_f32 on gfx950), RNE
__device__ __forceinline__ unsigned int pk_bf16(float a, float b) {
    union { __hip_bfloat162 h; unsigned int u; } c;
    c.h = __float22bfloat162_rn(float2{a, b});
    return c.u;
}

__device__ __forceinline__ short8 cvt8v(float4 a, float4 b) {
    union { short8 s; unsigned int u[4]; } c;
    c.u[0] = pk_bf16(a.x, a.y); c.u[1] = pk_bf16(a.z, a.w);
    c.u[2] = pk_bf16(b.x, b.y); c.u[3] = pk_bf16(b.z, b.w);
    return c.s;
}

// async global->LDS, 16B per lane; lds base wave-uniform, lane i lands at +i*16
__device__ __forceinline__ void async_ld16(const unsigned short* g, unsigned short* l) {
    __builtin_amdgcn_global_load_lds((const GLOBAL_AS unsigned int*)g,
                                     (LDS_AS unsigned int*)l, 16, 0, 0);
}

// counted vmcnt wait + raw barrier (T4): never drain the prefetch queue
#define WAITV(N) asm volatile("s_waitcnt vmcnt(" #N ")" ::: "memory")
#define BARSYNC() do { __builtin_amdgcn_s_barrier(); __builtin_amdgcn_sched_barrier(0); } while (0)

// ---------------------------------------------------------------------------
// Elementwise f32 -> bf16 (RNE). 8 elems/thread.
// ---------------------------------------------------------------------------
__global__ __launch_bounds__(256) void cvt_bf16(
    const float* __restrict__ src, unsigned short* __restrict__ dst)
{
    const size_t i = ((size_t)blockIdx.x * 256 + threadIdx.x) * 8;
    float4 a = *(const float4*)(src + i);
    float4 b = *(const float4*)(src + i + 4);
    *(short8*)(dst + i) = cvt8v(a, b);
}

// ---------------------------------------------------------------------------
// Transpose+convert: dst[n][k] bf16 = src[k][n] f32. Grid (N/64, K/64).
// ---------------------------------------------------------------------------
__global__ __launch_bounds__(256) void transpose_cvt(
    const float* __restrict__ src, unsigned short* __restrict__ dst, int K, int N)
{
    __shared__ unsigned short t[64][72];
    const int tid = threadIdx.x;
    const int n0 = blockIdx.x * 64, k0 = blockIdx.y * 64;
    #pragma unroll
    for (int it = 0; it < 4; ++it) {
        int r = it * 16 + (tid >> 4);
        int c = (tid & 15) * 4;
        float4 v = *(const float4*)(src + (size_t)(k0 + r) * N + n0 + c);
        t[r][c] = f2bf(v.x); t[r][c + 1] = f2bf(v.y);
        t[r][c + 2] = f2bf(v.z); t[r][c + 3] = f2bf(v.w);
    }
    __syncthreads();
    const int nr = tid >> 2, kg = (tid & 3) * 16;
    short8 o0, o1;
    #pragma unroll
    for (int j = 0; j < 8; ++j) { o0[j] = (short)t[kg + j][nr]; o1[j] = (short)t[kg + 8 + j][nr]; }
    *(short8*)(dst + (size_t)(n0 + nr) * K + k0 + kg) = o0;
    *(short8*)(dst + (size_t)(n0 + nr) * K + k0 + kg + 8) = o1;
}

// ---------------------------------------------------------------------------
// GEMM (round-6 proven, for GEMM1): 128x128 tile, BK=64, single-buffered,
// 2 barriers/step, all-async bf16; XCD chunk swizzle + XOR bank swizzle.
// ---------------------------------------------------------------------------
template<bool OUT_F32>
__global__ __launch_bounds__(256, 3) void gemm_bt(
    const unsigned short* __restrict__ Ab, const unsigned short* __restrict__ Bt,
    void* __restrict__ Cv, int M, int N, int K)
{
    __shared__ __align__(16) unsigned short As[128][64];
    __shared__ __align__(16) unsigned short Bs[128][64];

    const int tid = threadIdx.x, lane = tid & 63, w = tid >> 6;
    const int quad = lane >> 4, l15 = lane & 15;

    const int nwg = gridDim.x * gridDim.y;
    int lin = blockIdx.y * gridDim.x + blockIdx.x;
    lin = (lin & 7) * (nwg >> 3) + (lin >> 3);
    const int m0 = (lin / gridDim.x) * 128, n0 = (lin % gridDim.x) * 128;

    const int rw = (w >> 1) * 64, cw = (w & 1) * 64;

    const f32x4 zero = {0.f, 0.f, 0.f, 0.f};
    f32x4 acc[4][4];
    #pragma unroll
    for (int i = 0; i < 4; ++i)
        #pragma unroll
        for (int j = 0; j < 4; ++j) acc[i][j] = zero;

    const int srow = lane >> 3;
    const int scol = ((lane & 7) ^ srow) * 8;

    const unsigned short* Asf = &As[0][0];
    const unsigned short* Bsf = &Bs[0][0];
    const int rx = (l15 & 7) << 3;

    #pragma unroll
    for (int c = 0; c < 4; ++c)
        async_ld16(Ab + (size_t)(m0 + w * 32 + c * 8 + srow) * K + scol,
                   &As[w * 32 + c * 8][0]);
    #pragma unroll
    for (int c = 0; c < 4; ++c)
        async_ld16(Bt + (size_t)(n0 + w * 32 + c * 8 + srow) * K + scol,
                   &Bs[w * 32 + c * 8][0]);

    for (int k0 = 0; k0 < K; k0 += 64) {
        __syncthreads();

        short8 af[4][2], bf2[4][2];
        #pragma unroll
        for (int i = 0; i < 4; ++i) {
            const int rb = (rw + i * 16 + l15) * 64;
            af[i][0] = *(const short8*)(Asf + ((rb + quad * 8) ^ rx));
            af[i][1] = *(const short8*)(Asf + ((rb + 32 + quad * 8) ^ rx));
        }
        #pragma unroll
        for (int j = 0; j < 4; ++j) {
            const int rb = (cw + j * 16 + l15) * 64;
            bf2[j][0] = *(const short8*)(Bsf + ((rb + quad * 8) ^ rx));
            bf2[j][1] = *(const short8*)(Bsf + ((rb + 32 + quad * 8) ^ rx));
        }
        __syncthreads();

        if (k0 + 64 < K) {
            #pragma unroll
            for (int c = 0; c < 4; ++c)
                async_ld16(Ab + (size_t)(m0 + w * 32 + c * 8 + srow) * K + k0 + 64 + scol,
                           &As[w * 32 + c * 8][0]);
            #pragma unroll
            for (int c = 0; c < 4; ++c)
                async_ld16(Bt + (size_t)(n0 + w * 32 + c * 8 + srow) * K + k0 + 64 + scol,
                           &Bs[w * 32 + c * 8][0]);
        }

        #pragma unroll
        for (int i = 0; i < 4; ++i)
            #pragma unroll
            for (int j = 0; j < 4; ++j) {
                acc[i][j] = __builtin_amdgcn_mfma_f32_16x16x32_bf16(af[i][0], bf2[j][0], acc[i][j], 0, 0, 0);
                acc[i][j] = __builtin_amdgcn_mfma_f32_16x16x32_bf16(af[i][1], bf2[j][1], acc[i][j], 0, 0, 0);
            }
    }

    #pragma unroll
    for (int i = 0; i < 4; ++i) {
        const int row = m0 + rw + i * 16 + quad * 4;
        #pragma unroll
        for (int j = 0; j < 4; ++j) {
            const int col = n0 + cw + j * 16 + l15;
            #pragma unroll
            for (int r = 0; r < 4; ++r) {
                if constexpr (OUT_F32)
                    ((float*)Cv)[(size_t)(row + r) * N + col] = acc[i][j][r];
                else
                    ((unsigned short*)Cv)[(size_t)(row + r) * N + col] = f2bf(acc[i][j][r]);
            }
        }
    }
}

// ---------------------------------------------------------------------------
// GEMM v9b (for GEMM2): 128x256 tile, BK=32, 512 thr / 8 waves (64x64 each,
// acc 4x4), TRIPLE-buffered LDS — now 3 x 24KB = 72KB (r12's 144KB was the
// one novel runtime artifact in the failed build; 72KB is inside the proven
// 74.5KB envelope). Counted vmcnt, prefetch distance 2, one barrier/tile:
//   prologue: stage t0->buf0, t1->buf1            (6 loads/wave out)
//   phase:    WAITV(3); BAR; stage t+2; compute t (invariant: 6 at each wait)
//   tail:     stages 62,63; waits 3,3,3,0 (hand-verified)
// Race audit: stage t+2 overwrites buf[(t+2)%3] = tile t-1's buffer, whose
// readers all passed this phase's barrier. Grid = 8x32 = 256 blocks = exactly
// 1 block/CU. Bank swizzle: r9's verified involution for 64B rows — write
// chunk (lane&3)^(row&3), read chunk quad^(l15&3). XCD chunk swizzle kept.
// ---------------------------------------------------------------------------
__device__ __forceinline__ void stg2(
    const unsigned short* __restrict__ Ag, const unsigned short* __restrict__ Bg,
    unsigned short (*Asb)[32], unsigned short (*Bsb)[32],
    int m0, int n0, int K, int k, int w, int lane)
{
    const int r4 = lane >> 2;                       // 0..15
    const int cc = ((lane & 3) ^ (r4 & 3)) * 8;     // swizzled 16B chunk
    async_ld16(Ag + (size_t)(m0 + w * 16 + r4) * K + k + cc, &Asb[w * 16][0]);
    #pragma unroll
    for (int c = 0; c < 2; ++c)
        async_ld16(Bg + (size_t)(n0 + c * 128 + w * 16 + r4) * K + k + cc,
                   &Bsb[c * 128 + w * 16][0]);
}

__device__ __forceinline__ void cmp2(
    const unsigned short (*Asb)[32], const unsigned short (*Bsb)[32],
    int wm, int wn, int l15, int quad, f32x4 acc[4][4])
{
    const int pc = (quad ^ (l15 & 3)) * 8;   // read-side swizzled chunk
    short8 af[4], bf[4];
    #pragma unroll
    for (int i = 0; i < 4; ++i)
        af[i] = *(const short8*)&Asb[wm * 64 + i * 16 + l15][pc];
    #pragma unroll
    for (int j = 0; j < 4; ++j)
        bf[j] = *(const short8*)&Bsb[wn * 64 + j * 16 + l15][pc];
    __builtin_amdgcn_s_setprio(1);
    #pragma unroll
    for (int i = 0; i < 4; ++i)
        #pragma unroll
        for (int j = 0; j < 4; ++j)
            acc[i][j] = __builtin_amdgcn_mfma_f32_16x16x32_bf16(af[i], bf[j], acc[i][j], 0, 0, 0);
    __builtin_amdgcn_s_setprio(0);
}

__global__ __launch_bounds__(512, 2) void gemm_bn256(
    const unsigned short* __restrict__ Ab, const unsigned short* __restrict__ Bt,
    float* __restrict__ Cv, int M, int N, int K)   // requires K == 2048
{
    __shared__ __align__(16) unsigned short As0[128][32], As1[128][32], As2[128][32];
    __shared__ __align__(16) unsigned short Bs0[256][32], Bs1[256][32], Bs2[256][32];

    const int tid = threadIdx.x, lane = tid & 63, w = tid >> 6;   // w: 0..7
    const int quad = lane >> 4, l15 = lane & 15;
    const int wm = w >> 2, wn = w & 3;   // wave output: rows wm*64, cols wn*64

    // XCD-chunked bijective swizzle (nwg = 256, %8 == 0)
    const int nwg = gridDim.x * gridDim.y;
    int lin = blockIdx.y * gridDim.x + blockIdx.x;
    lin = (lin & 7) * (nwg >> 3) + (lin >> 3);
    const int m0 = (lin / gridDim.x) * 128, n0 = (lin % gridDim.x) * 256;

    const f32x4 zero = {0.f, 0.f, 0.f, 0.f};
    f32x4 acc[4][4];
    #pragma unroll
    for (int i = 0; i < 4; ++i)
        #pragma unroll
        for (int j = 0; j < 4; ++j) acc[i][j] = zero;

    // prologue: tiles 0 -> buf0, 1 -> buf1 (6 loads/wave out)
    stg2(Ab, Bt, As0, Bs0, m0, n0, K, 0,  w, lane);
    stg2(Ab, Bt, As1, Bs1, m0, n0, K, 32, w, lane);

    // body: 20 iterations x 3 phases = tiles 0..59; stage through tile 61
    int t = 0;
    #pragma unroll 1
    for (int it = 0; it < 20; ++it) {
        WAITV(3); BARSYNC();
        stg2(Ab, Bt, As2, Bs2, m0, n0, K, (t + 2) * 32, w, lane);
        cmp2(As0, Bs0, wm, wn, l15, quad, acc);

        WAITV(3); BARSYNC();
        stg2(Ab, Bt, As0, Bs0, m0, n0, K, (t + 3) * 32, w, lane);
        cmp2(As1, Bs1, wm, wn, l15, quad, acc);

        WAITV(3); BARSYNC();
        stg2(Ab, Bt, As1, Bs1, m0, n0, K, (t + 4) * 32, w, lane);
        cmp2(As2, Bs2, wm, wn, l15, quad, acc);

        t += 3;
    }

    // tail: tiles 60..63 (bufs 0,1,2,0); stage 62,63; waits 3,3,3,0
    WAITV(3); BARSYNC();
    stg2(Ab, Bt, As2, Bs2, m0, n0, K, 62 * 32, w, lane);
    cmp2(As0, Bs0, wm, wn, l15, quad, acc);

    WAITV(3); BARSYNC();
    stg2(Ab, Bt, As0, Bs0, m0, n0, K, 63 * 32, w, lane);
    cmp2(As1, Bs1, wm, wn, l15, quad, acc);

    WAITV(3); BARSYNC();
    cmp2(As2, Bs2, wm, wn, l15, quad, acc);

    WAITV(0); BARSYNC();
    cmp2(As0, Bs0, wm, wn, l15, quad, acc);

    #pragma unroll
    for (int i = 0; i < 4; ++i) {
        const int row = m0 + wm * 64 + i * 16 + quad * 4;
        #pragma unroll
        for (int j = 0; j < 4; ++j) {
            const int col = n0 + wn * 64 + j * 16 + l15;
            #pragma unroll
            for (int r = 0; r < 4; ++r)
                Cv[(size_t)(row + r) * N + col] = acc[i][j][r];
        }
    }
}

// ---------------------------------------------------------------------------
// Flash MQA v6 (proven KVBLK=32 version): swapped-operand QK^T, in-register
// P pack, K/V double-buffered, one barrier/iter, O^T epilogue transpose.
// ---------------------------------------------------------------------------
__global__ __launch_bounds__(256) void mqa_flash(
    const unsigned short* __restrict__ qkv,  // [B*S, 2304] bf16
    unsigned short* __restrict__ attn)       // [B*S, 2048] bf16
{
    const int S = 2048, QKVW = 2304;
    __shared__ __align__(16) union {
        struct {
            unsigned short Ks[2][32][136];   // [buf][permuted key][d]
            unsigned short VT[2][144][44];   // [buf][d][key]; rows 128..143 ones
        } s;
        unsigned short T[4][32][136];        // epilogue per-wave O transpose
    } sm;

    const int tid = threadIdx.x, lane = tid & 63, w = tid >> 6;
    const int quad = lane >> 4, l15 = lane & 15;
    const int bid = blockIdx.x;
    const int qb = bid & 15;          // 16 q-blocks of 128 rows
    const int h  = (bid >> 4) & 15;
    const int b  = bid >> 8;

    for (int i = tid; i < 2 * 16 * 32; i += 256)
        sm.s.VT[i >> 9][128 + ((i >> 5) & 15)][i & 31] = 0x3F80;

    const unsigned short* base = qkv + (size_t)b * S * QKVW;

    short8 qf[2][4];
    #pragma unroll
    for (int sub = 0; sub < 2; ++sub) {
        const int row = qb * 128 + w * 32 + sub * 16 + l15;
        #pragma unroll
        for (int ds = 0; ds < 4; ++ds)
            qf[sub][ds] = *(const short8*)(base + (size_t)row * QKVW + h * 128 + ds * 32 + quad * 8);
    }

    const f32x4 zero = {0.f, 0.f, 0.f, 0.f};
    f32x4 o[2][9];
    #pragma unroll
    for (int sub = 0; sub < 2; ++sub)
        #pragma unroll
        for (int d = 0; d < 9; ++d) o[sub][d] = zero;

    const int krow = tid & 31, kdg = tid >> 5;
    const int kpr  = ((krow & 1) << 4) | (krow >> 1);
    const int vkp  = tid & 15, vdg = tid >> 4;

    const unsigned short* kp = base + (size_t)krow * QKVW + 2048 + kdg * 16;
    const unsigned short* vp = base + (size_t)(2 * vkp) * QKVW + 2176 + vdg * 8;

    short8 k0v = *(const short8*)kp;
    short8 k1v = *(const short8*)(kp + 8);
    short8 v0v = *(const short8*)vp;
    short8 v1v = *(const short8*)(vp + QKVW);

    for (int kb = 0; kb < S; kb += 32) {
        const int p = (kb >> 5) & 1;

        *(short8*)(&sm.s.Ks[p][kpr][kdg * 16]) = k0v;
        *(short8*)(&sm.s.Ks[p][kpr][kdg * 16 + 8]) = k1v;
        #pragma unroll
        for (int j = 0; j < 8; ++j) {
            unsigned int pkv = (unsigned int)(unsigned short)v0v[j]
                             | ((unsigned int)(unsigned short)v1v[j] << 16);
            *(unsigned int*)(&sm.s.VT[p][vdg * 8 + j][vkp * 2]) = pkv;
        }

        if (kb + 32 < S) {
            kp += 32 * QKVW; vp += 32 * QKVW;
            k0v = *(const short8*)kp;
            k1v = *(const short8*)(kp + 8);
            v0v = *(const short8*)vp;
            v1v = *(const short8*)(vp + QKVW);
        }

        __syncthreads();

        __builtin_amdgcn_s_setprio(1);

        f32x4 sc[2][2];
        sc[0][0] = zero; sc[0][1] = zero; sc[1][0] = zero; sc[1][1] = zero;
        #pragma unroll
        for (int ds = 0; ds < 4; ++ds) {
            short8 kf0 = *(const short8*)(&sm.s.Ks[p][l15][ds * 32 + quad * 8]);
            short8 kf1 = *(const short8*)(&sm.s.Ks[p][16 + l15][ds * 32 + quad * 8]);
            #pragma unroll
            for (int sub = 0; sub < 2; ++sub) {
                sc[sub][0] = __builtin_amdgcn_mfma_f32_16x16x32_bf16(kf0, qf[sub][ds], sc[sub][0], 0, 0, 0);
                sc[sub][1] = __builtin_amdgcn_mfma_f32_16x16x32_bf16(kf1, qf[sub][ds], sc[sub][1], 0, 0, 0);
            }
        }

        const float scale = 0.08838834764831845f;  // 128^-0.5
        short8 pf[2];
        #pragma unroll
        for (int sub = 0; sub < 2; ++sub) {
            union { short8 sv; unsigned int u[4]; } c;
            #pragma unroll
            for (int r = 0; r < 4; ++r) {
                float e0 = __expf(fmaf(sc[sub][0][r], scale, -12.f));
                float e1 = __expf(fmaf(sc[sub][1][r], scale, -12.f));
                c.u[r] = pk_bf16(e0, e1);
            }
            pf[sub] = c.sv;
        }

        #pragma unroll
        for (int dsub = 0; dsub < 9; ++dsub) {
            short8 vf = *(const short8*)(&sm.s.VT[p][dsub * 16 + l15][quad * 8]);
            o[0][dsub] = __builtin_amdgcn_mfma_f32_16x16x32_bf16(vf, pf[0], o[0][dsub], 0, 0, 0);
            o[1][dsub] = __builtin_amdgcn_mfma_f32_16x16x32_bf16(vf, pf[1], o[1][dsub], 0, 0, 0);
        }

        __builtin_amdgcn_s_setprio(0);
    }

    __syncthreads();

    #pragma unroll
    for (int sub = 0; sub < 2; ++sub) {
        const float inv = 1.0f / o[sub][8][0];
        #pragma unroll
        for (int dsub = 0; dsub < 8; ++dsub) {
            unsigned int lo = pk_bf16(o[sub][dsub][0] * inv, o[sub][dsub][1] * inv);
            unsigned int hi = pk_bf16(o[sub][dsub][2] * inv, o[sub][dsub][3] * inv);
            unsigned int* dst = (unsigned int*)&sm.T[w][sub * 16 + l15][dsub * 16 + quad * 4];
            dst[0] = lo; dst[1] = hi;
        }
    }
    __syncthreads();

    const size_t rowbase = (size_t)b * S + qb * 128 + w * 32;
    #pragma unroll
    for (int pass = 0; pass < 8; ++pass) {
        const int row = pass * 4 + quad;
        short8 ov = *(const short8*)(&sm.T[w][row][l15 * 8]);
        *(short8*)(&attn[(rowbase + row) * 2048 + h * 128 + l15 * 8]) = ov;
    }
}

// ---------------------------------------------------------------------------
// ws layout (ushort units), total 35.65 MB (proven-safe footprint):
//   R0 [0, 9437184): qkv bf16 [4096][2304]; after mqa, woutT [2048][2048] reuses it
//   R1 [9437184, 17825792): wattnT [2304][2048] during GEMM1; attn [4096][2048] after
// xb (bf16 of x, [4096][2048]) lives in the FIRST HALF OF d_out (dead until GEMM2).
// ---------------------------------------------------------------------------
extern "C" void kernel_launch(void* const* d_in, const int* in_sizes, int n_in,
                              void* d_out, int out_size, void* d_ws, size_t ws_size,
                              hipStream_t stream)
{
    const float* x     = (const float*)d_in[0];   // [2,2048,2048] f32 = [4096][2048]
    const float* wattn = (const float*)d_in[1];   // [2048][2304] f32
    const float* wout  = (const float*)d_in[2];   // [2048][2048] f32
    float* out = (float*)d_out;                   // [4096][2048] f32

    unsigned short* ws = (unsigned short*)d_ws;
    unsigned short* qkv    = ws;                        // R0
    unsigned short* woutT  = ws;                        // R0 (after mqa)
    unsigned short* wattnT = ws + (size_t)9437184;      // R1
    unsigned short* attn   = ws + (size_t)9437184;      // R1 (after GEMM1)
    unsigned short* xb     = (unsigned short*)d_out;    // scratch until GEMM2

    // 0) xb = bf16(x)
    cvt_bf16<<<dim3(4096), 256, 0, stream>>>(x, xb);
    // 1) wattnT[n][k] = bf16(w_attn[k][n])
    transpose_cvt<<<dim3(2304 / 64, 2048 / 64), 256, 0, stream>>>(wattn, wattnT, 2048, 2304);
    // 2) qkv = xb @ w_attn   (r6-proven 128x128 kernel)
    gemm_bt<false><<<dim3(2304 / 128, 4096 / 128), 256, 0, stream>>>(
        xb, wattnT, qkv, 4096, 2304, 2048);
    // 3) flash MQA (v6)
    mqa_flash<<<dim3(2 * 16 * 16), 256, 0, stream>>>(qkv, attn);
    // 4) woutT[n][k] = bf16(w_out[k][n])
    transpose_cvt<<<dim3(2048 / 64, 2048 / 64), 256, 0, stream>>>(wout, woutT, 2048, 2048);
    // 5) out = attn @ w_out  (128x256 8-wave triple-buffer, 72KB LDS, 1 blk/CU)
    gemm_bn256<<<dim3(2048 / 256, 4096 / 128), 512, 0, stream>>>(
        attn, woutT, out, 4096, 2048, 2048);
}